// Round 7
// baseline (590.272 us; speedup 1.0000x reference)
//
#include <hip/hip_runtime.h>

#define NBATCH 2
#define SEQ 2048
#define EMBED 1024
#define HEADS 16
#define HDIM 64

typedef short s16x8 __attribute__((ext_vector_type(8)));
typedef float f32x4 __attribute__((ext_vector_type(4)));
typedef unsigned short u16;

__device__ __forceinline__ u16 f2bf(float f) {
    union { float f; unsigned u; } v; v.f = f;
    unsigned r = v.u + 0x7FFFu + ((v.u >> 16) & 1u);
    return (u16)(r >> 16);
}
// 8 consecutive f32 -> bf16x8 fragment (RNE)
__device__ __forceinline__ s16x8 f8bf(const float* p) {
    const float4 a = *(const float4*)p;
    const float4 b = *(const float4*)(p + 4);
    s16x8 r;
    r[0] = (short)f2bf(a.x); r[1] = (short)f2bf(a.y);
    r[2] = (short)f2bf(a.z); r[3] = (short)f2bf(a.w);
    r[4] = (short)f2bf(b.x); r[5] = (short)f2bf(b.y);
    r[6] = (short)f2bf(b.z); r[7] = (short)f2bf(b.w);
    return r;
}

// ---------------- per-head K/V projection: out = x_head @ W^T + b ------------
__global__ __launch_bounds__(256) void proj_kernel(
    const float* __restrict__ x, const float* __restrict__ W,
    const float* __restrict__ bias, u16* __restrict__ out, int transpose)
{
    const int wv = threadIdx.x >> 6;
    const int lane = threadIdx.x & 63;
    const int lr = lane & 15, lg = lane >> 4;
    const int nh = blockIdx.y, n = nh >> 4, h = nh & 15;
    const int lbase = blockIdx.x * 64 + wv * 16;

    const float* xrow = x + ((size_t)(n * SEQ + lbase + lr)) * EMBED + h * HDIM;
    const s16x8 a0 = f8bf(xrow + lg * 8);
    const s16x8 a1 = f8bf(xrow + 32 + lg * 8);

#pragma unroll
    for (int eb = 0; eb < 4; ++eb) {
        const float* wrow = W + (eb * 16 + lr) * HDIM;
        const s16x8 b0 = f8bf(wrow + lg * 8);
        const s16x8 b1 = f8bf(wrow + 32 + lg * 8);
        f32x4 c = {0.f, 0.f, 0.f, 0.f};
        c = __builtin_amdgcn_mfma_f32_16x16x32_bf16(a0, b0, c, 0, 0, 0);
        c = __builtin_amdgcn_mfma_f32_16x16x32_bf16(a1, b1, c, 0, 0, 0);
        const int col = eb * 16 + lr;
        const float bv = bias[col];
        if (!transpose) {
#pragma unroll
            for (int r = 0; r < 4; ++r) {
                const int row = lbase + lg * 4 + r;
                out[((size_t)nh * SEQ + row) * HDIM + col] = f2bf(c[r] + bv);
            }
        } else {
#pragma unroll
            for (int r = 0; r < 4; ++r) {
                const int row = lbase + lg * 4 + r;
                out[((size_t)nh * HDIM + col) * SEQ + row] = f2bf(c[r] + bv);
            }
        }
    }
}

// ---------------- attention with fused Q-projection --------------------------
__global__ __launch_bounds__(256) void attn_kernel(
    const float* __restrict__ xq, const float* __restrict__ Wq,
    const float* __restrict__ bq,
    const u16* __restrict__ Kp, const u16* __restrict__ Vt,
    const int* __restrict__ mask, float* __restrict__ Xo)
{
    __shared__ __align__(16) u16 qlds[4][16 * 64];
    __shared__ __align__(16) u16 plds[4][16 * 32];
    const int wv = threadIdx.x >> 6;
    const int lane = threadIdx.x & 63;
    const int lr = lane & 15, lg = lane >> 4;
    const int nh = blockIdx.y, n = nh >> 4, h = nh & 15;
    const int qbase = blockIdx.x * 64 + wv * 16;

    // fused Q projection, staged through LDS into A-frag layout
    {
        const float* xrow = xq + ((size_t)(n * SEQ + qbase + lr)) * EMBED + h * HDIM;
        const s16x8 a0 = f8bf(xrow + lg * 8);
        const s16x8 a1 = f8bf(xrow + 32 + lg * 8);
#pragma unroll
        for (int eb = 0; eb < 4; ++eb) {
            const float* wrow = Wq + (eb * 16 + lr) * HDIM;
            const s16x8 b0 = f8bf(wrow + lg * 8);
            const s16x8 b1 = f8bf(wrow + 32 + lg * 8);
            f32x4 c = {0.f, 0.f, 0.f, 0.f};
            c = __builtin_amdgcn_mfma_f32_16x16x32_bf16(a0, b0, c, 0, 0, 0);
            c = __builtin_amdgcn_mfma_f32_16x16x32_bf16(a1, b1, c, 0, 0, 0);
            const int col = eb * 16 + lr;
            const float bv = bq[col];
#pragma unroll
            for (int r = 0; r < 4; ++r)
                qlds[wv][(lg * 4 + r) * 64 + col] = f2bf(c[r] + bv);
        }
    }
    __syncthreads();
    const s16x8 aq0 = *(const s16x8*)(&qlds[wv][lr * 64 + lg * 8]);
    const s16x8 aq1 = *(const s16x8*)(&qlds[wv][lr * 64 + 32 + lg * 8]);

    const int* mbase = mask + (size_t)n * SEQ * SEQ;
    const u16* vbase = Vt + (size_t)nh * HDIM * SEQ;

    float m_[4], ls[4];
    f32x4 o_[4];
#pragma unroll
    for (int r = 0; r < 4; ++r) { m_[r] = -1e30f; ls[r] = 0.f; }
#pragma unroll
    for (int db = 0; db < 4; ++db) o_[db] = (f32x4){0.f, 0.f, 0.f, 0.f};

    const float inv32 = 1.0f / 32.0f;   // scale by sqrt(EMBED)=32
    const float NEGS  = -3.125e18f;     // -1e20/32 (mask BEFORE scale)
    u16* pb = plds[wv];

    for (int kb = 0; kb < SEQ; kb += 32) {
        const u16* krow0 = Kp + ((size_t)nh * SEQ + kb + lr) * HDIM;
        const u16* krow1 = krow0 + 16 * HDIM;
        f32x4 s0 = {0.f, 0.f, 0.f, 0.f}, s1 = {0.f, 0.f, 0.f, 0.f};
        s0 = __builtin_amdgcn_mfma_f32_16x16x32_bf16(aq0, *(const s16x8*)(krow0 + lg * 8), s0, 0, 0, 0);
        s0 = __builtin_amdgcn_mfma_f32_16x16x32_bf16(aq1, *(const s16x8*)(krow0 + 32 + lg * 8), s0, 0, 0, 0);
        s1 = __builtin_amdgcn_mfma_f32_16x16x32_bf16(aq0, *(const s16x8*)(krow1 + lg * 8), s1, 0, 0, 0);
        s1 = __builtin_amdgcn_mfma_f32_16x16x32_bf16(aq1, *(const s16x8*)(krow1 + 32 + lg * 8), s1, 0, 0, 0);

        float tm[4];
#pragma unroll
        for (int r = 0; r < 4; ++r) {
            const int qr = qbase + lg * 4 + r;
            const int* mp = mbase + (size_t)qr * SEQ + kb;
            s0[r] = mp[lr]      ? s0[r] * inv32 : NEGS;
            s1[r] = mp[16 + lr] ? s1[r] * inv32 : NEGS;
            tm[r] = fmaxf(s0[r], s1[r]);
        }
#pragma unroll
        for (int off = 1; off < 16; off <<= 1)
#pragma unroll
            for (int r = 0; r < 4; ++r) tm[r] = fmaxf(tm[r], __shfl_xor(tm[r], off));

        float sc[4], rs[4];
        f32x4 p0, p1;
#pragma unroll
        for (int r = 0; r < 4; ++r) {
            const float mn = fmaxf(m_[r], tm[r]);
            sc[r] = __expf(m_[r] - mn);
            m_[r] = mn;
            p0[r] = __expf(s0[r] - mn);
            p1[r] = __expf(s1[r] - mn);
            rs[r] = p0[r] + p1[r];
        }
#pragma unroll
        for (int off = 1; off < 16; off <<= 1)
#pragma unroll
            for (int r = 0; r < 4; ++r) rs[r] += __shfl_xor(rs[r], off);
#pragma unroll
        for (int r = 0; r < 4; ++r) ls[r] = ls[r] * sc[r] + rs[r];
#pragma unroll
        for (int db = 0; db < 4; ++db)
#pragma unroll
            for (int r = 0; r < 4; ++r) o_[db][r] *= sc[r];

        __syncthreads();
#pragma unroll
        for (int r = 0; r < 4; ++r) {
            pb[(lg * 4 + r) * 32 + lr]      = f2bf(p0[r]);
            pb[(lg * 4 + r) * 32 + 16 + lr] = f2bf(p1[r]);
        }
        __syncthreads();
        const s16x8 pa = *(const s16x8*)(pb + lr * 32 + lg * 8);

#pragma unroll
        for (int db = 0; db < 4; ++db) {
            const s16x8 vb = *(const s16x8*)(vbase + (size_t)(db * 16 + lr) * SEQ + kb + lg * 8);
            o_[db] = __builtin_amdgcn_mfma_f32_16x16x32_bf16(pa, vb, o_[db], 0, 0, 0);
        }
    }

#pragma unroll
    for (int r = 0; r < 4; ++r) {
        const float inv = 1.0f / ls[r];
        const int qr = qbase + lg * 4 + r;
        float* orow = Xo + ((size_t)n * SEQ + qr) * EMBED + h * HDIM;
#pragma unroll
        for (int db = 0; db < 4; ++db)
            orow[db * 16 + lr] = o_[db][r] * inv;
    }
}

// ---------------- output projection, f32 VALU: out = X @ Wo^T + bo -----------
__global__ __launch_bounds__(256) void outproj_valu(
    const float* __restrict__ X, const float* __restrict__ Wo,
    const float* __restrict__ bo, float* __restrict__ out)
{
    __shared__ float xs[64][33];
    __shared__ float wt[64][33];
    const int rbase = blockIdx.y * 64, cbase = blockIdx.x * 64;
    const int t = threadIdx.x;
    const int rg = t >> 4, cg = t & 15;

    float acc[4][4];
#pragma unroll
    for (int i = 0; i < 4; ++i)
#pragma unroll
        for (int j = 0; j < 4; ++j) acc[i][j] = 0.f;

    for (int e0 = 0; e0 < EMBED; e0 += 32) {
        __syncthreads();
        for (int idx = t; idx < 64 * 32; idx += 256) {
            const int rl = idx >> 5, el = idx & 31;
            xs[rl][el] = X[(size_t)(rbase + rl) * EMBED + e0 + el];
            wt[rl][el] = Wo[(size_t)(cbase + rl) * EMBED + e0 + el];
        }
        __syncthreads();
#pragma unroll 8
        for (int e = 0; e < 32; ++e) {
            float xv[4], wv[4];
#pragma unroll
            for (int i = 0; i < 4; ++i) xv[i] = xs[rg * 4 + i][e];
#pragma unroll
            for (int j = 0; j < 4; ++j) wv[j] = wt[cg * 4 + j][e];
#pragma unroll
            for (int i = 0; i < 4; ++i)
#pragma unroll
                for (int j = 0; j < 4; ++j) acc[i][j] += xv[i] * wv[j];
        }
    }
#pragma unroll
    for (int i = 0; i < 4; ++i) {
        const int r = rbase + rg * 4 + i;
#pragma unroll
        for (int j = 0; j < 4; ++j) {
            const int c = cbase + cg * 4 + j;
            out[(size_t)r * EMBED + c] = acc[i][j] + bo[c];
        }
    }
}

extern "C" void kernel_launch(void* const* d_in, const int* in_sizes, int n_in,
                              void* d_out, int out_size, void* d_ws, size_t ws_size,
                              hipStream_t stream)
{
    const float* q    = (const float*)d_in[0];
    const float* k    = (const float*)d_in[1];
    const float* v    = (const float*)d_in[2];
    const int*  mask  = (const int*)d_in[3];
    const float* Wq   = (const float*)d_in[4];
    const float* bq   = (const float*)d_in[5];
    const float* Wk   = (const float*)d_in[6];
    const float* bk   = (const float*)d_in[7];
    const float* Wv   = (const float*)d_in[8];
    const float* bv   = (const float*)d_in[9];
    const float* Wo   = (const float*)d_in[10];
    const float* bo   = (const float*)d_in[11];

    u16* ws = (u16*)d_ws;
    const size_t per = (size_t)NBATCH * HEADS * SEQ * HDIM;  // 4.19M elems
    u16*   Kp  = ws;                         // [N*H][L][D] bf16
    u16*   Vt  = ws + per;                   // [N*H][D][L] bf16
    float* Xof = (float*)(ws + 2 * per);     // [N][L][EMBED] f32
    // ws bytes: 2*per*2 + per*4 = 33.6 MB (same envelope as rounds 2-4)

    const dim3 pgrid(SEQ / 64, NBATCH * HEADS);
    proj_kernel<<<pgrid, 256, 0, stream>>>(k, Wk, bk, Kp, 0);
    proj_kernel<<<pgrid, 256, 0, stream>>>(v, Wv, bv, Vt, 1);
    attn_kernel<<<dim3(SEQ / 64, NBATCH * HEADS), 256, 0, stream>>>(q, Wq, bq, Kp, Vt, mask, Xof);
    outproj_valu<<<dim3(EMBED / 64, NBATCH * SEQ / 64), 256, 0, stream>>>(Xof, Wo, bo, (float*)d_out);
}

// Round 8
// 478.037 us; speedup vs baseline: 1.2348x; 1.2348x over previous
//
#include <hip/hip_runtime.h>

#define NBATCH 2
#define SEQ 2048
#define EMBED 1024
#define HEADS 16
#define HDIM 64

typedef _Float16 h16x8 __attribute__((ext_vector_type(8)));
typedef _Float16 h16x4 __attribute__((ext_vector_type(4)));
typedef float f32x4 __attribute__((ext_vector_type(4)));
typedef unsigned long long u64;

// 8 consecutive f32 -> f16x8 fragment (RNE via v_cvt_f16_f32)
__device__ __forceinline__ h16x8 f8h(const float* p) {
    const float4 a = *(const float4*)p;
    const float4 b = *(const float4*)(p + 4);
    h16x8 r;
    r[0] = (_Float16)a.x; r[1] = (_Float16)a.y;
    r[2] = (_Float16)a.z; r[3] = (_Float16)a.w;
    r[4] = (_Float16)b.x; r[5] = (_Float16)b.y;
    r[6] = (_Float16)b.z; r[7] = (_Float16)b.w;
    return r;
}

// ---------------- mask int32 -> bit-packed u64 (1 bit/key) -------------------
__global__ __launch_bounds__(256) void maskpack(const int* __restrict__ m,
                                                u64* __restrict__ mb)
{
    const size_t i = (size_t)blockIdx.x * 256 + threadIdx.x;
    const u64 b = __ballot(m[i] != 0);
    if ((threadIdx.x & 63) == 0) mb[i >> 6] = b;
}

// ---------------- f32 -> f16 bulk convert (Wo) -------------------------------
__global__ __launch_bounds__(256) void cvt16(const float* __restrict__ in,
                                             _Float16* __restrict__ out, int n)
{
    const int i = (blockIdx.x * 256 + threadIdx.x) * 4;
    if (i < n) {
        const float4 v = *(const float4*)(in + i);
        h16x4 o;
        o[0] = (_Float16)v.x; o[1] = (_Float16)v.y;
        o[2] = (_Float16)v.z; o[3] = (_Float16)v.w;
        *(h16x4*)(out + i) = o;
    }
}

// ---------------- per-head K/V projection: out = x_head @ W^T + b ------------
__global__ __launch_bounds__(256) void proj_kernel(
    const float* __restrict__ x, const float* __restrict__ W,
    const float* __restrict__ bias, _Float16* __restrict__ out, int transpose)
{
    const int wv = threadIdx.x >> 6;
    const int lane = threadIdx.x & 63;
    const int lr = lane & 15, lg = lane >> 4;
    const int nh = blockIdx.y, n = nh >> 4, h = nh & 15;
    const int lbase = blockIdx.x * 64 + wv * 16;

    const float* xrow = x + ((size_t)(n * SEQ + lbase + lr)) * EMBED + h * HDIM;
    const h16x8 a0 = f8h(xrow + lg * 8);
    const h16x8 a1 = f8h(xrow + 32 + lg * 8);

#pragma unroll
    for (int eb = 0; eb < 4; ++eb) {
        const float* wrow = W + (eb * 16 + lr) * HDIM;
        const h16x8 b0 = f8h(wrow + lg * 8);
        const h16x8 b1 = f8h(wrow + 32 + lg * 8);
        f32x4 c = {0.f, 0.f, 0.f, 0.f};
        c = __builtin_amdgcn_mfma_f32_16x16x32_f16(a0, b0, c, 0, 0, 0);
        c = __builtin_amdgcn_mfma_f32_16x16x32_f16(a1, b1, c, 0, 0, 0);
        const int col = eb * 16 + lr;
        const float bv = bias[col];
        if (!transpose) {
#pragma unroll
            for (int r = 0; r < 4; ++r) {
                const int row = lbase + lg * 4 + r;
                out[((size_t)nh * SEQ + row) * HDIM + col] = (_Float16)(c[r] + bv);
            }
        } else {
#pragma unroll
            for (int r = 0; r < 4; ++r) {
                const int row = lbase + lg * 4 + r;
                out[((size_t)nh * HDIM + col) * SEQ + row] = (_Float16)(c[r] + bv);
            }
        }
    }
}

// ---------------- attention, fused Q-proj, KVBLK=64, barrier-free K-loop -----
// Per-wave LDS tiles (qlds/plds) -> wave-local lgkmcnt fence instead of
// __syncthreads (validated: r2 fence version == r3 barrier version bitwise).
// XOR swizzle elem^=((row&7)<<3) breaks the 128B-row ds_read_b128 conflict.
__global__ __launch_bounds__(256) void attn_kernel(
    const float* __restrict__ xq, const float* __restrict__ Wq,
    const float* __restrict__ bq,
    const _Float16* __restrict__ Kp, const _Float16* __restrict__ Vt,
    const u64* __restrict__ mbits, _Float16* __restrict__ Xo)
{
    __shared__ __align__(16) _Float16 qlds[4][16 * 64];
    __shared__ __align__(16) _Float16 plds[4][16 * 64];
    const int wv = threadIdx.x >> 6;
    const int lane = threadIdx.x & 63;
    const int lr = lane & 15, lg = lane >> 4;
    const int nh = blockIdx.y, n = nh >> 4, h = nh & 15;
    const int qbase = blockIdx.x * 64 + wv * 16;

    _Float16* qb_ = qlds[wv];
    _Float16* pb_ = plds[wv];

    // ---- fused Q projection -> swizzled qlds ----
    {
        const float* xrow = xq + ((size_t)(n * SEQ + qbase + lr)) * EMBED + h * HDIM;
        const h16x8 a0 = f8h(xrow + lg * 8);
        const h16x8 a1 = f8h(xrow + 32 + lg * 8);
#pragma unroll
        for (int eb = 0; eb < 4; ++eb) {
            const float* wrow = Wq + (eb * 16 + lr) * HDIM;
            const h16x8 b0 = f8h(wrow + lg * 8);
            const h16x8 b1 = f8h(wrow + 32 + lg * 8);
            f32x4 c = {0.f, 0.f, 0.f, 0.f};
            c = __builtin_amdgcn_mfma_f32_16x16x32_f16(a0, b0, c, 0, 0, 0);
            c = __builtin_amdgcn_mfma_f32_16x16x32_f16(a1, b1, c, 0, 0, 0);
            const int col = eb * 16 + lr;
            const float bv = bq[col];
#pragma unroll
            for (int r = 0; r < 4; ++r) {
                const int row = lg * 4 + r;
                qb_[(row * 64 + col) ^ ((row & 7) << 3)] = (_Float16)(c[r] + bv);
            }
        }
    }
    asm volatile("s_waitcnt lgkmcnt(0)" ::: "memory");
    __builtin_amdgcn_sched_barrier(0);
    const h16x8 aq0 = *(const h16x8*)(qb_ + ((lr * 64 + lg * 8) ^ ((lr & 7) << 3)));
    const h16x8 aq1 = *(const h16x8*)(qb_ + ((lr * 64 + 32 + lg * 8) ^ ((lr & 7) << 3)));

    const u64* mrow = mbits + (size_t)n * SEQ * (SEQ / 64);
    const _Float16* kbase = Kp + (size_t)nh * SEQ * HDIM;
    const _Float16* vbase = Vt + (size_t)nh * HDIM * SEQ;

    float m_[4], ls[4];
    f32x4 o_[4];
#pragma unroll
    for (int r = 0; r < 4; ++r) { m_[r] = -1e30f; ls[r] = 0.f; }
#pragma unroll
    for (int db = 0; db < 4; ++db) o_[db] = (f32x4){0.f, 0.f, 0.f, 0.f};

    const float inv32 = 1.0f / 32.0f;   // scale by sqrt(EMBED)=32
    const float NEGS  = -3.125e18f;     // -1e20/32 (mask BEFORE scale)

    for (int kb = 0; kb < SEQ; kb += 64) {
        // ---- scores: 4 col-groups of 16 keys ----
        f32x4 s[4];
#pragma unroll
        for (int sg = 0; sg < 4; ++sg) {
            const _Float16* kr = kbase + (size_t)(kb + sg * 16 + lr) * HDIM;
            f32x4 c = {0.f, 0.f, 0.f, 0.f};
            c = __builtin_amdgcn_mfma_f32_16x16x32_f16(aq0, *(const h16x8*)(kr + lg * 8), c, 0, 0, 0);
            c = __builtin_amdgcn_mfma_f32_16x16x32_f16(aq1, *(const h16x8*)(kr + 32 + lg * 8), c, 0, 0, 0);
            s[sg] = c;
        }

        // ---- mask (bit-packed, before scale) + row max ----
        float tm[4];
#pragma unroll
        for (int r = 0; r < 4; ++r) {
            const int qr = qbase + lg * 4 + r;
            const u64 mw = mrow[(size_t)qr * (SEQ / 64) + (kb >> 6)];
            float t = -3.0e38f;
#pragma unroll
            for (int sg = 0; sg < 4; ++sg) {
                const bool on = (mw >> (sg * 16 + lr)) & 1ull;
                s[sg][r] = on ? s[sg][r] * inv32 : NEGS;
                t = fmaxf(t, s[sg][r]);
            }
            tm[r] = t;
        }
#pragma unroll
        for (int off = 1; off < 16; off <<= 1)
#pragma unroll
            for (int r = 0; r < 4; ++r) tm[r] = fmaxf(tm[r], __shfl_xor(tm[r], off));

        // ---- online softmax update; P -> swizzled LDS as it's produced ----
        float sc[4], rs[4];
#pragma unroll
        for (int r = 0; r < 4; ++r) {
            const float mn = fmaxf(m_[r], tm[r]);
            sc[r] = __expf(m_[r] - mn);
            m_[r] = mn;
            rs[r] = 0.f;
        }
#pragma unroll
        for (int sg = 0; sg < 4; ++sg)
#pragma unroll
            for (int r = 0; r < 4; ++r) {
                const float p = __expf(s[sg][r] - m_[r]);
                rs[r] += p;
                const int row = lg * 4 + r;
                pb_[(row * 64 + sg * 16 + lr) ^ ((row & 7) << 3)] = (_Float16)p;
            }
#pragma unroll
        for (int off = 1; off < 16; off <<= 1)
#pragma unroll
            for (int r = 0; r < 4; ++r) rs[r] += __shfl_xor(rs[r], off);
#pragma unroll
        for (int r = 0; r < 4; ++r) ls[r] = ls[r] * sc[r] + rs[r];
#pragma unroll
        for (int db = 0; db < 4; ++db)
#pragma unroll
            for (int r = 0; r < 4; ++r) o_[db][r] *= sc[r];

        // ---- wave-local fence; P A-frags; O += P @ V ----
        asm volatile("s_waitcnt lgkmcnt(0)" ::: "memory");
        __builtin_amdgcn_sched_barrier(0);
        const h16x8 pa0 = *(const h16x8*)(pb_ + ((lr * 64 + lg * 8) ^ ((lr & 7) << 3)));
        const h16x8 pa1 = *(const h16x8*)(pb_ + ((lr * 64 + 32 + lg * 8) ^ ((lr & 7) << 3)));

#pragma unroll
        for (int db = 0; db < 4; ++db) {
            const _Float16* vr = vbase + (size_t)(db * 16 + lr) * SEQ + kb;
            o_[db] = __builtin_amdgcn_mfma_f32_16x16x32_f16(pa0, *(const h16x8*)(vr + lg * 8), o_[db], 0, 0, 0);
            o_[db] = __builtin_amdgcn_mfma_f32_16x16x32_f16(pa1, *(const h16x8*)(vr + 32 + lg * 8), o_[db], 0, 0, 0);
        }
    }

    // ---- epilogue: O / l -> f16 ----
#pragma unroll
    for (int r = 0; r < 4; ++r) {
        const float inv = 1.0f / ls[r];
        const int qr = qbase + lg * 4 + r;
        _Float16* orow = Xo + ((size_t)n * SEQ + qr) * EMBED + h * HDIM;
#pragma unroll
        for (int db = 0; db < 4; ++db)
            orow[db * 16 + lr] = (_Float16)(o_[db][r] * inv);
    }
}

// ---------------- output projection, f16 MFMA: out = X @ Wo^T + bo -----------
__global__ __launch_bounds__(256) void outproj_mfma(
    const _Float16* __restrict__ X, const _Float16* __restrict__ Wo16,
    const float* __restrict__ bo, float* __restrict__ out)
{
    const int wv = threadIdx.x >> 6;
    const int lane = threadIdx.x & 63;
    const int lr = lane & 15, lg = lane >> 4;
    const int rbase = blockIdx.y * 64 + wv * 16;
    const int cbase = blockIdx.x * 64;

    f32x4 acc[4];
#pragma unroll
    for (int cb = 0; cb < 4; ++cb) acc[cb] = (f32x4){0.f, 0.f, 0.f, 0.f};

    const _Float16* xrow = X + (size_t)(rbase + lr) * EMBED;
    for (int k0 = 0; k0 < EMBED; k0 += 32) {
        const h16x8 a = *(const h16x8*)(xrow + k0 + lg * 8);
#pragma unroll
        for (int cb = 0; cb < 4; ++cb) {
            const h16x8 b = *(const h16x8*)(Wo16 + (size_t)(cbase + cb * 16 + lr) * EMBED + k0 + lg * 8);
            acc[cb] = __builtin_amdgcn_mfma_f32_16x16x32_f16(a, b, acc[cb], 0, 0, 0);
        }
    }
#pragma unroll
    for (int cb = 0; cb < 4; ++cb) {
        const int col = cbase + cb * 16 + lr;
        const float bv = bo[col];
#pragma unroll
        for (int r = 0; r < 4; ++r) {
            const int row = rbase + lg * 4 + r;
            out[(size_t)row * EMBED + col] = acc[cb][r] + bv;
        }
    }
}

extern "C" void kernel_launch(void* const* d_in, const int* in_sizes, int n_in,
                              void* d_out, int out_size, void* d_ws, size_t ws_size,
                              hipStream_t stream)
{
    const float* q    = (const float*)d_in[0];
    const float* k    = (const float*)d_in[1];
    const float* v    = (const float*)d_in[2];
    const int*  mask  = (const int*)d_in[3];
    const float* Wq   = (const float*)d_in[4];
    const float* bq   = (const float*)d_in[5];
    const float* Wk   = (const float*)d_in[6];
    const float* bk   = (const float*)d_in[7];
    const float* Wv   = (const float*)d_in[8];
    const float* bv   = (const float*)d_in[9];
    const float* Wo   = (const float*)d_in[10];
    const float* bo   = (const float*)d_in[11];

    const size_t per = (size_t)NBATCH * HEADS * SEQ * HDIM;       // 4.19M elems
    const size_t nmask = (size_t)NBATCH * SEQ * SEQ;              // 8.39M bits src
    u64*      mbits = (u64*)d_ws;                                 // 1 MB
    _Float16* Kp    = (_Float16*)(mbits + nmask / 64);            // [N*H][L][D]
    _Float16* Vt    = Kp + per;                                   // [N*H][D][L]
    _Float16* Xh    = Vt + per;                                   // [N][L][EMBED]
    _Float16* Wo16  = Xh + per;                                   // [E][E]
    // total ws: 1MB + 3*8.39MB + 2MB = 28.2 MB

    maskpack<<<(int)(nmask / 256), 256, 0, stream>>>(mask, mbits);
    cvt16<<<EMBED * EMBED / 1024, 256, 0, stream>>>(Wo, Wo16, EMBED * EMBED);
    const dim3 pgrid(SEQ / 64, NBATCH * HEADS);
    proj_kernel<<<pgrid, 256, 0, stream>>>(k, Wk, bk, Kp, 0);
    proj_kernel<<<pgrid, 256, 0, stream>>>(v, Wv, bv, Vt, 1);
    attn_kernel<<<dim3(SEQ / 64, NBATCH * HEADS), 256, 0, stream>>>(q, Wq, bq, Kp, Vt, mbits, Xh);
    outproj_mfma<<<dim3(EMBED / 64, NBATCH * SEQ / 64), 256, 0, stream>>>(Xh, Wo16, bo, (float*)d_out);
}